// Round 1
// baseline (117.552 us; speedup 1.0000x reference)
//
#include <hip/hip_runtime.h>

#define OUT_N 8192
#define IN_N 8192
#define BATCH 16
#define CHUNK 512
#define NCHUNK (IN_N / CHUNK)   // 16
#define QROW (IN_N / 2)         // 4096 packed elems per output row

// Each block: 256 threads = 4 waves, handles 16 output rows (4 per wave).
// x (16 x 8192 fp32) staged chunk-wise into double-buffered LDS.
// q_packed delivered as int32 (one byte value 0..255 per element).
__global__ __launch_bounds__(256) void qlin_kernel(
    const float* __restrict__ x,
    const int*   __restrict__ qp,
    const float* __restrict__ scale,
    const float* __restrict__ bias,
    float* __restrict__ out)
{
    __shared__ float xbuf[2][BATCH][CHUNK];   // 2 * 16 * 512 * 4B = 64 KB

    const int t    = threadIdx.x;
    const int wave = t >> 6;
    const int lane = t & 63;
    const int rows_base = blockIdx.x * 16 + wave * 4;

    float acc[16][4];
    #pragma unroll
    for (int b = 0; b < 16; ++b)
        #pragma unroll
        for (int r = 0; r < 4; ++r) acc[b][r] = 0.f;

    // ---- prologue: stage chunk 0 into xbuf[0] (coalesced float4)
    #pragma unroll
    for (int j = 0; j < 8; ++j) {
        int idx = t + j * 256;                 // float4 index within chunk
        int b = idx >> 7, rem = idx & 127;     // 128 float4 per row-chunk
        float4 v = *(const float4*)(x + b * IN_N + rem * 4);
        *(float4*)(&xbuf[0][b][rem * 4]) = v;
    }

    // ---- prefetch q for chunk 0
    // lane covers i-pairs {2*lane + 128*k, +1}, k=0..3 -> packed elem lane + 64*k
    int qv[16];
    #pragma unroll
    for (int r = 0; r < 4; ++r)
        #pragma unroll
        for (int k = 0; k < 4; ++k)
            qv[r * 4 + k] = qp[(rows_base + r) * QROW + lane + 64 * k];

    for (int c = 0; c < NCHUNK; ++c) {
        const int buf = c & 1;
        __syncthreads();                        // xbuf[buf] ready

        const bool more = (c + 1 < NCHUNK);

        // issue next chunk's global x loads early (latency hidden under FMAs)
        float4 sreg[8];
        if (more) {
            #pragma unroll
            for (int j = 0; j < 8; ++j) {
                int idx = t + j * 256;
                int b = idx >> 7, rem = idx & 127;
                sreg[j] = *(const float4*)(x + b * IN_N + (c + 1) * CHUNK + rem * 4);
            }
        }
        // prefetch next chunk's q
        int qn[16];
        if (more) {
            #pragma unroll
            for (int r = 0; r < 4; ++r)
                #pragma unroll
                for (int k = 0; k < 4; ++k)
                    qn[r * 4 + k] = qp[(rows_base + r) * QROW + (c + 1) * 256 + lane + 64 * k];
        }

        // unpack current q: lo nibble = even i, hi nibble = odd i, signed 4-bit
        float we[16], wo[16];
        #pragma unroll
        for (int m = 0; m < 16; ++m) {
            int v = qv[m];
            we[m] = (float)(((v & 15) ^ 8) - 8);
            wo[m] = (float)((((v >> 4) & 15) ^ 8) - 8);
        }

        // compute: 64 ds_read_b64 + 512 FMA per lane per chunk
        #pragma unroll
        for (int b = 0; b < 16; ++b) {
            #pragma unroll
            for (int k = 0; k < 4; ++k) {
                float2 xv = *(const float2*)(&xbuf[buf][b][2 * lane + 128 * k]);
                #pragma unroll
                for (int r = 0; r < 4; ++r) {
                    acc[b][r] += xv.x * we[r * 4 + k];
                    acc[b][r] += xv.y * wo[r * 4 + k];
                }
            }
        }

        // write staged x into the other buffer (vmcnt wait overlapped w/ FMAs above)
        if (more) {
            #pragma unroll
            for (int j = 0; j < 8; ++j) {
                int idx = t + j * 256;
                int b = idx >> 7, rem = idx & 127;
                *(float4*)(&xbuf[buf ^ 1][b][rem * 4]) = sreg[j];
            }
            #pragma unroll
            for (int m = 0; m < 16; ++m) qv[m] = qn[m];
        }
    }

    // ---- epilogue: full 64-lane butterfly reduce for each of 64 partials
    float keep = 0.f;
    #pragma unroll
    for (int b = 0; b < 16; ++b) {
        #pragma unroll
        for (int r = 0; r < 4; ++r) {
            float v = acc[b][r];
            v += __shfl_xor(v, 32);
            v += __shfl_xor(v, 16);
            v += __shfl_xor(v, 8);
            v += __shfl_xor(v, 4);
            v += __shfl_xor(v, 2);
            v += __shfl_xor(v, 1);
            if (lane == b * 4 + r) keep = v;
        }
    }
    const int o  = rows_base + (lane & 3);
    const int bi = lane >> 2;
    out[bi * OUT_N + o] = keep * scale[o >> 7] + bias[o];
}

extern "C" void kernel_launch(void* const* d_in, const int* in_sizes, int n_in,
                              void* d_out, int out_size, void* d_ws, size_t ws_size,
                              hipStream_t stream) {
    (void)in_sizes; (void)n_in; (void)d_ws; (void)ws_size; (void)out_size;
    const float* x     = (const float*)d_in[0];
    const int*   qp    = (const int*)d_in[1];
    const float* scale = (const float*)d_in[2];
    const float* bias  = (const float*)d_in[3];
    float*       out   = (float*)d_out;

    qlin_kernel<<<dim3(OUT_N / 16), dim3(256), 0, stream>>>(x, qp, scale, bias, out);
}

// Round 3
// 48.771 us; speedup vs baseline: 2.4103x; 2.4103x over previous
//
#include <hip/hip_runtime.h>
#include <hip/hip_bf16.h>

#define OUT_N 8192
#define IN_N  8192
#define QROW  (IN_N / 2)          // int32 elems per out row (one byte value each)
#define KSPLIT 4
#define KPW   (IN_N / KSPLIT)     // K range per wave = 2048
#define KSTEPS (KPW / 32)         // 64 mfma steps per wave

typedef __attribute__((ext_vector_type(8))) short short8v;  // 8 bf16 (4 VGPRs)
typedef __attribute__((ext_vector_type(4))) float f32x4;

// pack two floats into one VGPR as (lo=bf16(a), hi=bf16(b)) with RNE
__device__ __forceinline__ unsigned int bf16pk(float a, float b) {
    __hip_bfloat162 h = __float22bfloat162_rn(make_float2(a, b));
    unsigned int u;
    __builtin_memcpy(&u, &h, 4);   // bit move; bit_cast rejects non-trivially-copyable
    return u;
}

// One block = one 16-column output tile. 4 waves split K=8192 into quarters.
// Per k-step (K=32): B-frag = 8 consecutive int4 weights of out-row (lane&15)
// from ONE dwordx4 of int32-widened q; A-frag = 8 consecutive fp32 x of batch
// row (lane&15) converted to bf16. A and B use the identical (lane,j)->k map,
// so the HW k-permutation cancels in the dot product.
__global__ __launch_bounds__(256) void qlin_mfma_kernel(
    const float* __restrict__ x,
    const int*   __restrict__ qp,
    const float* __restrict__ scale,
    const float* __restrict__ bias,
    float* __restrict__ out)
{
    const int t = threadIdx.x;
    const int w = t >> 6;          // wave id -> K quarter
    const int l = t & 63;
    const int g = l >> 4;          // lane group 0..3
    const int r = l & 15;          // A: batch row, B: out row within tile
    const int tile = blockIdx.x;

    // int32 index of this lane's q dwordx4 for step s: qbase + s*16
    const int qbase = (tile * 16 + r) * QROW + w * (KPW / 2) + g * 4;
    // float index of this lane's x float8 for step s: xbase + s*32
    const int xbase = r * IN_N + w * KPW + g * 8;

    f32x4 acc = {0.f, 0.f, 0.f, 0.f};

    // depth-2 software pipeline (16 KB q in flight per CU > BW*latency ~9 KB)
    int4   qc, qn1;
    float4 xac, xbc, xan1, xbn1;
    qc   = *(const int4*)  (qp + qbase);
    xac  = *(const float4*)(x  + xbase);
    xbc  = *(const float4*)(x  + xbase + 4);
    qn1  = *(const int4*)  (qp + qbase + 16);
    xan1 = *(const float4*)(x  + xbase + 32);
    xbn1 = *(const float4*)(x  + xbase + 36);

    #pragma unroll 2
    for (int s = 0; s < KSTEPS; ++s) {
        const int sp = (s + 2 < KSTEPS) ? s + 2 : KSTEPS - 1;
        int4   qn2  = *(const int4*)  (qp + qbase + sp * 16);
        float4 xan2 = *(const float4*)(x  + xbase + sp * 32);
        float4 xbn2 = *(const float4*)(x  + xbase + sp * 32 + 4);

        // B fragment: nibble e=2m is lo, e=2m+1 is hi of byte m; signed 4-bit
        // int -> f32 -> bf16 is exact for |v| <= 8
        unsigned int ub0 = bf16pk((float)((qc.x << 28) >> 28), (float)((qc.x << 24) >> 28));
        unsigned int ub1 = bf16pk((float)((qc.y << 28) >> 28), (float)((qc.y << 24) >> 28));
        unsigned int ub2 = bf16pk((float)((qc.z << 28) >> 28), (float)((qc.z << 24) >> 28));
        unsigned int ub3 = bf16pk((float)((qc.w << 28) >> 28), (float)((qc.w << 24) >> 28));
        uint4 ub = {ub0, ub1, ub2, ub3};
        short8v bfrag = __builtin_bit_cast(short8v, ub);

        // A fragment: 8 fp32 -> 8 bf16 (RNE via cvt_pk)
        uint4 ua = { bf16pk(xac.x, xac.y), bf16pk(xac.z, xac.w),
                     bf16pk(xbc.x, xbc.y), bf16pk(xbc.z, xbc.w) };
        short8v afrag = __builtin_bit_cast(short8v, ua);

        acc = __builtin_amdgcn_mfma_f32_16x16x32_bf16(afrag, bfrag, acc, 0, 0, 0);

        // rotate pipeline registers (statically renamed under unroll)
        qc  = qn1;  xac  = xan1; xbc  = xbn1;
        qn1 = qn2;  xan1 = xan2; xbn1 = xbn2;
    }

    // cross-wave K reduction: D mapping is row=(lane>>4)*4+j (batch), col=lane&15 (out)
    __shared__ float red[KSPLIT][16][16];
    red[w][g * 4 + 0][r] = acc[0];
    red[w][g * 4 + 1][r] = acc[1];
    red[w][g * 4 + 2][r] = acc[2];
    red[w][g * 4 + 3][r] = acc[3];
    __syncthreads();

    const int b = t >> 4;          // batch
    const int o = t & 15;          // out within tile
    const int oc = tile * 16 + o;
    float v = red[0][b][o] + red[1][b][o] + red[2][b][o] + red[3][b][o];
    out[b * OUT_N + oc] = v * scale[oc >> 7] + bias[oc];
}

extern "C" void kernel_launch(void* const* d_in, const int* in_sizes, int n_in,
                              void* d_out, int out_size, void* d_ws, size_t ws_size,
                              hipStream_t stream) {
    (void)in_sizes; (void)n_in; (void)d_ws; (void)ws_size; (void)out_size;
    const float* x     = (const float*)d_in[0];
    const int*   qp    = (const int*)d_in[1];
    const float* scale = (const float*)d_in[2];
    const float* bias  = (const float*)d_in[3];
    float*       out   = (float*)d_out;

    qlin_mfma_kernel<<<dim3(OUT_N / 16), dim3(256), 0, stream>>>(x, qp, scale, bias, out);
}

// Round 4
// 40.131 us; speedup vs baseline: 2.9292x; 1.2153x over previous
//
#include <hip/hip_runtime.h>
#include <hip/hip_bf16.h>

#define OUT_N 8192
#define IN_N  8192
#define QROW  (IN_N / 2)        // int32 elems per out row (one widened byte each)
#define WAVES 8                 // K-split ways per block
#define KPW   (IN_N / WAVES)    // 1024 in-elems per wave
#define KSTEPS (KPW / 32)       // 32 mfma steps per wave
#define GRP   4                 // k-steps per prefetch group
#define NGRP  (KSTEPS / GRP)    // 8 groups

typedef __attribute__((ext_vector_type(8))) short short8v;  // 8 bf16
typedef __attribute__((ext_vector_type(4))) float f32x4;

__device__ __forceinline__ unsigned int bf16pk(float a, float b) {
    __hip_bfloat162 h = __float22bfloat162_rn(make_float2(a, b));
    unsigned int u;
    __builtin_memcpy(&u, &h, 4);
    return u;
}

// Pre-pass: x fp32 -> bf16 row-major [16][8192] in d_ws (256 KB, L2-hot).
__global__ __launch_bounds__(256) void xconv_kernel(
    const float* __restrict__ x, unsigned short* __restrict__ xb)
{
    int i = (blockIdx.x * 256 + threadIdx.x) * 4;
    float4 v = *(const float4*)(x + i);
    uint2 u = { bf16pk(v.x, v.y), bf16pk(v.z, v.w) };
    *(uint2*)(xb + i) = u;
}

// One block = one 16-out-row tile; 8 waves split K=8192 into 1024-wide ranges.
// Per k-step: B-frag = one dwordx4 of widened q (8 int4 weights of out-row
// lane&15, unpacked to bf16); A-frag = one dwordx4 of pre-converted bf16 x.
// A and B share the identical (lane,j)->k map, so any HW k-permutation cancels.
__global__ __launch_bounds__(512, 4) void qlin_mfma_kernel(
    const int*            __restrict__ qp,
    const unsigned short* __restrict__ xb,
    const float*          __restrict__ scale,
    const float*          __restrict__ bias,
    float*                __restrict__ out)
{
    const int t = threadIdx.x;
    const int w = t >> 6;           // wave id -> K range
    const int l = t & 63;
    const int g = l >> 4;           // lane group 0..3 (k sub-offset)
    const int r = l & 15;           // A: batch row, B: out row within tile
    const int tile = blockIdx.x;

    // per-step strides: q advances 16 int32 (=4 int4), x advances 32 bf16 (=4 uint4)
    const int4*  qP = (const int4*) (qp + (tile * 16 + r) * QROW + w * (KPW / 2) + g * 4);
    const uint4* xP = (const uint4*)(xb + (size_t)r * IN_N + w * KPW + g * 8);

    f32x4 acc = {0.f, 0.f, 0.f, 0.f};

    int4  qr[2][GRP];
    uint4 xr[2][GRP];

    // prologue: group 0
    #pragma unroll
    for (int j = 0; j < GRP; ++j) { qr[0][j] = qP[j * 4]; xr[0][j] = xP[j * 4]; }

    #pragma unroll   // full unroll: all buffer indices compile-time (no scratch)
    for (int c = 0; c < NGRP; ++c) {
        const int cur = c & 1, nxt = cur ^ 1;
        if (c + 1 < NGRP) {
            #pragma unroll
            for (int j = 0; j < GRP; ++j) {
                const int s = (c + 1) * GRP + j;
                qr[nxt][j] = qP[s * 4];
                xr[nxt][j] = xP[s * 4];
            }
        }
        #pragma unroll
        for (int j = 0; j < GRP; ++j) {
            const int4 q = qr[cur][j];
            // nibble e=2m is lo, e=2m+1 is hi of byte m; signed; exact in bf16
            uint4 ub = {
                bf16pk((float)((q.x << 28) >> 28), (float)((q.x << 24) >> 28)),
                bf16pk((float)((q.y << 28) >> 28), (float)((q.y << 24) >> 28)),
                bf16pk((float)((q.z << 28) >> 28), (float)((q.z << 24) >> 28)),
                bf16pk((float)((q.w << 28) >> 28), (float)((q.w << 24) >> 28))
            };
            short8v bfrag = __builtin_bit_cast(short8v, ub);
            short8v afrag = __builtin_bit_cast(short8v, xr[cur][j]);
            acc = __builtin_amdgcn_mfma_f32_16x16x32_bf16(afrag, bfrag, acc, 0, 0, 0);
        }
    }

    // cross-wave K reduction; D mapping: col=lane&15 (out), row=(lane>>4)*4+j (batch)
    __shared__ float red[WAVES][16][17];   // +1 pad: conflict-free epilogue stores
    red[w][g * 4 + 0][r] = acc[0];
    red[w][g * 4 + 1][r] = acc[1];
    red[w][g * 4 + 2][r] = acc[2];
    red[w][g * 4 + 3][r] = acc[3];
    __syncthreads();

    if (t < 256) {
        const int b = t >> 4;           // batch
        const int o = t & 15;           // out within tile
        const int oc = tile * 16 + o;
        float v = 0.f;
        #pragma unroll
        for (int i = 0; i < WAVES; ++i) v += red[i][b][o];
        out[b * OUT_N + oc] = v * scale[oc >> 7] + bias[oc];
    }
}

extern "C" void kernel_launch(void* const* d_in, const int* in_sizes, int n_in,
                              void* d_out, int out_size, void* d_ws, size_t ws_size,
                              hipStream_t stream) {
    (void)in_sizes; (void)n_in; (void)ws_size; (void)out_size;
    const float* x     = (const float*)d_in[0];
    const int*   qp    = (const int*)d_in[1];
    const float* scale = (const float*)d_in[2];
    const float* bias  = (const float*)d_in[3];
    float*       out   = (float*)d_out;
    unsigned short* xb = (unsigned short*)d_ws;   // 256 KB bf16 x

    xconv_kernel<<<dim3((16 * IN_N) / (256 * 4)), dim3(256), 0, stream>>>(x, xb);
    qlin_mfma_kernel<<<dim3(OUT_N / 16), dim3(512), 0, stream>>>(qp, xb, scale, bias, out);
}